// Round 1
// baseline (392.343 us; speedup 1.0000x reference)
//
#include <hip/hip_runtime.h>

// Fused 2-layer GRU + FC for (B=4096, L=128, IN=16, H=128, NC=24).
// 256 blocks x 512 threads; block = 16 batch rows, wave w owns h-cols [16w,16w+16).
// Weights live in VGPR MFMA B-fragments (fp16); h state in fp32 lane registers;
// h1/h2 double-buffered fp16 in LDS; x staged in 32-step chunks.

typedef _Float16 half_t;
typedef _Float16 half8 __attribute__((ext_vector_type(8)));
typedef _Float16 half4v __attribute__((ext_vector_type(4)));
typedef float f32x4 __attribute__((ext_vector_type(4)));

#define BB 16      // batch rows per block
#define HS 136     // h row stride (halves): 128 + 8 pad -> 2-way-max banks
#define XS 520     // x chunk row stride (halves): 32*16 + 8 pad
#define NSTEP 128

static __device__ __forceinline__ f32x4 mfma16(half8 a, half8 b, f32x4 c) {
  return __builtin_amdgcn_mfma_f32_16x16x32_f16(a, b, c, 0, 0, 0);
}

static __device__ __forceinline__ half8 zero8() {
  half8 v;
#pragma unroll
  for (int i = 0; i < 8; ++i) v[i] = (half_t)0.f;
  return v;
}

// load 8 consecutive fp32, convert to fp16 fragment
static __device__ __forceinline__ half8 ldw8(const float* __restrict__ p) {
  float4 a = *(const float4*)p;
  float4 b = *(const float4*)(p + 4);
  half8 r;
  r[0] = (half_t)a.x; r[1] = (half_t)a.y; r[2] = (half_t)a.z; r[3] = (half_t)a.w;
  r[4] = (half_t)b.x; r[5] = (half_t)b.y; r[6] = (half_t)b.z; r[7] = (half_t)b.w;
  return r;
}

static __device__ __forceinline__ float sigm(float v) {
  return __fdividef(1.f, 1.f + __expf(-v));
}
static __device__ __forceinline__ float tanh_fast(float v) {
  return fmaf(2.f, __fdividef(1.f, 1.f + __expf(-2.f * v)), -1.f);
}

__global__ __launch_bounds__(512) void gru_fused(
    const float* __restrict__ x,                                   // (4096,2,1024)
    const float* __restrict__ wih1, const float* __restrict__ whh1, // (384,16),(384,128)
    const float* __restrict__ bih1, const float* __restrict__ bhh1,
    const float* __restrict__ wih2, const float* __restrict__ whh2, // (384,128)x2
    const float* __restrict__ bih2, const float* __restrict__ bhh2,
    const float* __restrict__ fcw, const float* __restrict__ fcb,   // (24,128),(24,)
    float* __restrict__ out)                                        // (4096,24)
{
  __shared__ __align__(16) half_t xl[BB][XS];        // 16640 B
  __shared__ __align__(16) half_t h1b[2][BB][HS];    //  8704 B
  __shared__ __align__(16) half_t h2b[2][BB][HS];    //  8704 B
  __shared__ float h2f[BB][129];                     //  8256 B

  const int tid = threadIdx.x;
  const int lane = tid & 63;
  const int wv = tid >> 6;      // wave 0..7
  const int q = lane >> 4;      // quad 0..3
  const int c = lane & 15;
  const int jc = wv * 16 + c;   // this lane's h-column (0..127)
  const int s0 = blockIdx.x * BB;

  // zero initial state buffers (buffer 0)
  for (int i = tid; i < BB * HS; i += 512) {
    ((half_t*)h1b[0])[i] = (half_t)0.f;
    ((half_t*)h2b[0])[i] = (half_t)0.f;
  }

  // biases (r/z fold b_ih+b_hh; n keeps them split for r*(Wh+b_hh) semantics)
  const float b1r  = bih1[jc]       + bhh1[jc];
  const float b1z  = bih1[128 + jc] + bhh1[128 + jc];
  const float b1in = bih1[256 + jc];
  const float b1hn = bhh1[256 + jc];
  const float b2r  = bih2[jc]       + bhh2[jc];
  const float b2z  = bih2[128 + jc] + bhh2[128 + jc];
  const float b2in = bih2[256 + jc];
  const float b2hn = bhh2[256 + jc];

  // weight B-fragments: lane holds W[n=jc(+g*128)][k = kk*32 + q*8 + j]
  half8 wi1r, wi1z, wi1n;
  if (q < 2) {  // real K=16, quads 2..3 are zero-pad
    wi1r = ldw8(wih1 + (0 * 128 + jc) * 16 + q * 8);
    wi1z = ldw8(wih1 + (1 * 128 + jc) * 16 + q * 8);
    wi1n = ldw8(wih1 + (2 * 128 + jc) * 16 + q * 8);
  } else {
    wi1r = zero8(); wi1z = zero8(); wi1n = zero8();
  }
  half8 wh1r[4], wh1z[4], wh1n[4], wi2r[4], wi2z[4], wi2n[4], wh2r[4], wh2z[4], wh2n[4];
#pragma unroll
  for (int kk = 0; kk < 4; ++kk) {
    const int ko = kk * 32 + q * 8;
    wh1r[kk] = ldw8(whh1 + (0 * 128 + jc) * 128 + ko);
    wh1z[kk] = ldw8(whh1 + (1 * 128 + jc) * 128 + ko);
    wh1n[kk] = ldw8(whh1 + (2 * 128 + jc) * 128 + ko);
    wi2r[kk] = ldw8(wih2 + (0 * 128 + jc) * 128 + ko);
    wi2z[kk] = ldw8(wih2 + (1 * 128 + jc) * 128 + ko);
    wi2n[kk] = ldw8(wih2 + (2 * 128 + jc) * 128 + ko);
    wh2r[kk] = ldw8(whh2 + (0 * 128 + jc) * 128 + ko);
    wh2z[kk] = ldw8(whh2 + (1 * 128 + jc) * 128 + ko);
    wh2n[kk] = ldw8(whh2 + (2 * 128 + jc) * 128 + ko);
  }

  // fp32 hidden state, lane-resident: rows m = 4q+r, col jc (C/D layout invariant)
  float h1p[4] = {0.f, 0.f, 0.f, 0.f};
  float h2p[4] = {0.f, 0.f, 0.f, 0.f};

#pragma unroll 2
  for (int t = 0; t < NSTEP; ++t) {
    if ((t & 31) == 0) {
      // stage x[s][ch][t*8 .. t*8+255] -> xl[s][tl*16 + ch*8 + k], fp16
#pragma unroll
      for (int i = 0; i < 4; ++i) {
        int idx = tid + i * 512;          // 0..2047 float4s
        int s = idx >> 7;
        int rem = idx & 127;
        int ch = rem >> 6;
        int i4 = rem & 63;
        const float4 v = *(const float4*)(x + (size_t)(s0 + s) * 2048 + ch * 1024 + t * 8 + i4 * 4);
        half4v hv;
        hv[0] = (half_t)v.x; hv[1] = (half_t)v.y; hv[2] = (half_t)v.z; hv[3] = (half_t)v.w;
        *(half4v*)&xl[s][(i4 >> 1) * 16 + ch * 8 + (i4 & 1) * 4] = hv;
      }
      __syncthreads();
    }
    const int rb = t & 1;
    const int wb = rb ^ 1;

    // ---------------- layer 1 ----------------
    f32x4 ar  = {b1r, b1r, b1r, b1r};
    f32x4 az  = {b1z, b1z, b1z, b1z};
    f32x4 ain = {b1in, b1in, b1in, b1in};
    f32x4 ahn = {b1hn, b1hn, b1hn, b1hn};
    {
      half8 ax = zero8();
      if (q < 2) ax = *(const half8*)&xl[c][(t & 31) * 16 + q * 8];
      ar  = mfma16(ax, wi1r, ar);
      az  = mfma16(ax, wi1z, az);
      ain = mfma16(ax, wi1n, ain);
    }
#pragma unroll
    for (int kk = 0; kk < 4; ++kk) {
      half8 ah = *(const half8*)&h1b[rb][c][kk * 32 + q * 8];
      ar  = mfma16(ah, wh1r[kk], ar);
      az  = mfma16(ah, wh1z[kk], az);
      ahn = mfma16(ah, wh1n[kk], ahn);
    }
#pragma unroll
    for (int r = 0; r < 4; ++r) {
      float rg = sigm(ar[r]);
      float zg = sigm(az[r]);
      float ng = tanh_fast(fmaf(rg, ahn[r], ain[r]));
      float hn = fmaf(zg, h1p[r] - ng, ng);   // (1-z)*n + z*h
      h1p[r] = hn;
      h1b[wb][q * 4 + r][jc] = (half_t)hn;
    }
    __syncthreads();  // h1_new visible

    // ---------------- layer 2 ----------------
    f32x4 cr  = {b2r, b2r, b2r, b2r};
    f32x4 cz  = {b2z, b2z, b2z, b2z};
    f32x4 cin = {b2in, b2in, b2in, b2in};
    f32x4 chn = {b2hn, b2hn, b2hn, b2hn};
#pragma unroll
    for (int kk = 0; kk < 4; ++kk) {
      half8 a1 = *(const half8*)&h1b[wb][c][kk * 32 + q * 8];  // h1_new
      half8 a2 = *(const half8*)&h2b[rb][c][kk * 32 + q * 8];  // h2_prev
      cr  = mfma16(a1, wi2r[kk], cr);
      cz  = mfma16(a1, wi2z[kk], cz);
      cin = mfma16(a1, wi2n[kk], cin);
      cr  = mfma16(a2, wh2r[kk], cr);
      cz  = mfma16(a2, wh2z[kk], cz);
      chn = mfma16(a2, wh2n[kk], chn);
    }
#pragma unroll
    for (int r = 0; r < 4; ++r) {
      float rg = sigm(cr[r]);
      float zg = sigm(cz[r]);
      float ng = tanh_fast(fmaf(rg, chn[r], cin[r]));
      float hn = fmaf(zg, h2p[r] - ng, ng);
      h2p[r] = hn;
      h2b[wb][q * 4 + r][jc] = (half_t)hn;
    }
    __syncthreads();  // h2_new visible for next step
  }

  // ---------------- FC epilogue (pure fp32) ----------------
#pragma unroll
  for (int r = 0; r < 4; ++r) h2f[q * 4 + r][jc] = h2p[r];
  __syncthreads();
  if (tid < 384) {
    const int m = tid & 15;
    const int cls = tid >> 4;  // 0..23
    const float* w = fcw + cls * 128;
    float acc = fcb[cls];
#pragma unroll 8
    for (int j = 0; j < 128; ++j) acc = fmaf(h2f[m][j], w[j], acc);
    out[(size_t)(s0 + m) * 24 + cls] = acc;
  }
}

extern "C" void kernel_launch(void* const* d_in, const int* in_sizes, int n_in,
                              void* d_out, int out_size, void* d_ws, size_t ws_size,
                              hipStream_t stream) {
  (void)in_sizes; (void)n_in; (void)d_ws; (void)ws_size; (void)out_size;
  const float* x    = (const float*)d_in[0];
  const float* wih1 = (const float*)d_in[1];
  const float* whh1 = (const float*)d_in[2];
  const float* bih1 = (const float*)d_in[3];
  const float* bhh1 = (const float*)d_in[4];
  const float* wih2 = (const float*)d_in[5];
  const float* whh2 = (const float*)d_in[6];
  const float* bih2 = (const float*)d_in[7];
  const float* bhh2 = (const float*)d_in[8];
  const float* fcw  = (const float*)d_in[9];
  const float* fcb  = (const float*)d_in[10];
  float* outp = (float*)d_out;
  gru_fused<<<dim3(256), dim3(512), 0, stream>>>(
      x, wih1, whh1, bih1, bhh1, wih2, whh2, bih2, bhh2, fcw, fcb, outp);
}

// Round 2
// 390.665 us; speedup vs baseline: 1.0043x; 1.0043x over previous
//
#include <hip/hip_runtime.h>

// Fused 2-layer GRU + FC for (B=4096, L=128, IN=16, H=128, NC=24).
// 256 blocks x 512 threads; block = 16 batch rows, wave w owns h-cols [16w,16w+16).
// Weights live in VGPR MFMA B-fragments (fp16); h state in fp32 lane registers;
// h1/h2 double-buffered fp16 in LDS; x staged in 32-step chunks.
//
// __launch_bounds__(512, 2): 8 waves/block => 2 waves/SIMD co-residency => the
// VGPR cap MUST be 256, not the default-heuristic 128. At 128 the 156 VGPRs of
// weight fragments spill to scratch and get re-loaded every timestep (round 1:
// WRITE_SIZE 13.2 MB of spill stores, VALUBusy 61%, 356 us).

typedef _Float16 half_t;
typedef _Float16 half8 __attribute__((ext_vector_type(8)));
typedef _Float16 half4v __attribute__((ext_vector_type(4)));
typedef float f32x4 __attribute__((ext_vector_type(4)));

#define BB 16      // batch rows per block
#define HS 136     // h row stride (halves)
#define XS 520     // x chunk row stride (halves): 32*16 + 8 pad
#define NSTEP 128

static __device__ __forceinline__ f32x4 mfma16(half8 a, half8 b, f32x4 c) {
  return __builtin_amdgcn_mfma_f32_16x16x32_f16(a, b, c, 0, 0, 0);
}

static __device__ __forceinline__ half8 zero8() {
  half8 v;
#pragma unroll
  for (int i = 0; i < 8; ++i) v[i] = (half_t)0.f;
  return v;
}

// load 8 consecutive fp32, convert to fp16 fragment
static __device__ __forceinline__ half8 ldw8(const float* __restrict__ p) {
  float4 a = *(const float4*)p;
  float4 b = *(const float4*)(p + 4);
  half8 r;
  r[0] = (half_t)a.x; r[1] = (half_t)a.y; r[2] = (half_t)a.z; r[3] = (half_t)a.w;
  r[4] = (half_t)b.x; r[5] = (half_t)b.y; r[6] = (half_t)b.z; r[7] = (half_t)b.w;
  return r;
}

static __device__ __forceinline__ float sigm(float v) {
  return __fdividef(1.f, 1.f + __expf(-v));
}
static __device__ __forceinline__ float tanh_fast(float v) {
  return fmaf(2.f, __fdividef(1.f, 1.f + __expf(-2.f * v)), -1.f);
}

__global__ __launch_bounds__(512, 2) void gru_fused(
    const float* __restrict__ x,                                   // (4096,2,1024)
    const float* __restrict__ wih1, const float* __restrict__ whh1, // (384,16),(384,128)
    const float* __restrict__ bih1, const float* __restrict__ bhh1,
    const float* __restrict__ wih2, const float* __restrict__ whh2, // (384,128)x2
    const float* __restrict__ bih2, const float* __restrict__ bhh2,
    const float* __restrict__ fcw, const float* __restrict__ fcb,   // (24,128),(24,)
    float* __restrict__ out)                                        // (4096,24)
{
  __shared__ __align__(16) half_t xl[BB][XS];        // 16640 B
  __shared__ __align__(16) half_t h1b[2][BB][HS];    //  8704 B
  __shared__ __align__(16) half_t h2b[2][BB][HS];    //  8704 B
  __shared__ float h2f[BB][129];                     //  8256 B

  const int tid = threadIdx.x;
  const int lane = tid & 63;
  const int wv = tid >> 6;      // wave 0..7
  const int q = lane >> 4;      // quad 0..3
  const int c = lane & 15;
  const int jc = wv * 16 + c;   // this lane's h-column (0..127)
  const int s0 = blockIdx.x * BB;

  // zero initial state buffers (buffer 0)
  for (int i = tid; i < BB * HS; i += 512) {
    ((half_t*)h1b[0])[i] = (half_t)0.f;
    ((half_t*)h2b[0])[i] = (half_t)0.f;
  }

  // biases (r/z fold b_ih+b_hh; n keeps them split for r*(Wh+b_hh) semantics)
  const float b1r  = bih1[jc]       + bhh1[jc];
  const float b1z  = bih1[128 + jc] + bhh1[128 + jc];
  const float b1in = bih1[256 + jc];
  const float b1hn = bhh1[256 + jc];
  const float b2r  = bih2[jc]       + bhh2[jc];
  const float b2z  = bih2[128 + jc] + bhh2[128 + jc];
  const float b2in = bih2[256 + jc];
  const float b2hn = bhh2[256 + jc];

  // weight B-fragments: lane holds W[n=jc(+g*128)][k = kk*32 + q*8 + j]
  half8 wi1r, wi1z, wi1n;
  if (q < 2) {  // real K=16, quads 2..3 are zero-pad
    wi1r = ldw8(wih1 + (0 * 128 + jc) * 16 + q * 8);
    wi1z = ldw8(wih1 + (1 * 128 + jc) * 16 + q * 8);
    wi1n = ldw8(wih1 + (2 * 128 + jc) * 16 + q * 8);
  } else {
    wi1r = zero8(); wi1z = zero8(); wi1n = zero8();
  }
  half8 wh1r[4], wh1z[4], wh1n[4], wi2r[4], wi2z[4], wi2n[4], wh2r[4], wh2z[4], wh2n[4];
#pragma unroll
  for (int kk = 0; kk < 4; ++kk) {
    const int ko = kk * 32 + q * 8;
    wh1r[kk] = ldw8(whh1 + (0 * 128 + jc) * 128 + ko);
    wh1z[kk] = ldw8(whh1 + (1 * 128 + jc) * 128 + ko);
    wh1n[kk] = ldw8(whh1 + (2 * 128 + jc) * 128 + ko);
    wi2r[kk] = ldw8(wih2 + (0 * 128 + jc) * 128 + ko);
    wi2z[kk] = ldw8(wih2 + (1 * 128 + jc) * 128 + ko);
    wi2n[kk] = ldw8(wih2 + (2 * 128 + jc) * 128 + ko);
    wh2r[kk] = ldw8(whh2 + (0 * 128 + jc) * 128 + ko);
    wh2z[kk] = ldw8(whh2 + (1 * 128 + jc) * 128 + ko);
    wh2n[kk] = ldw8(whh2 + (2 * 128 + jc) * 128 + ko);
  }

  // fp32 hidden state, lane-resident: rows m = 4q+r, col jc (C/D layout invariant)
  float h1p[4] = {0.f, 0.f, 0.f, 0.f};
  float h2p[4] = {0.f, 0.f, 0.f, 0.f};

  for (int tc = 0; tc < NSTEP / 32; ++tc) {
    // stage x[s][ch][tc*256 .. +255] -> xl[s][tl*16 + ch*8 + k], fp16
#pragma unroll
    for (int i = 0; i < 4; ++i) {
      int idx = tid + i * 512;          // 0..2047 float4s
      int s = idx >> 7;
      int rem = idx & 127;
      int ch = rem >> 6;
      int i4 = rem & 63;
      const float4 v = *(const float4*)(x + (size_t)(s0 + s) * 2048 + ch * 1024 + tc * 256 + i4 * 4);
      half4v hv;
      hv[0] = (half_t)v.x; hv[1] = (half_t)v.y; hv[2] = (half_t)v.z; hv[3] = (half_t)v.w;
      *(half4v*)&xl[s][(i4 >> 1) * 16 + ch * 8 + (i4 & 1) * 4] = hv;
    }
    __syncthreads();

    for (int tt = 0; tt < 32; ++tt) {
      const int t = tc * 32 + tt;
      const int rb = t & 1;
      const int wb = rb ^ 1;

      // ---------------- layer 1 ----------------
      f32x4 ar  = {b1r, b1r, b1r, b1r};
      f32x4 az  = {b1z, b1z, b1z, b1z};
      f32x4 ain = {b1in, b1in, b1in, b1in};
      f32x4 ahn = {b1hn, b1hn, b1hn, b1hn};
      {
        half8 ax = zero8();
        if (q < 2) ax = *(const half8*)&xl[c][tt * 16 + q * 8];
        ar  = mfma16(ax, wi1r, ar);
        az  = mfma16(ax, wi1z, az);
        ain = mfma16(ax, wi1n, ain);
      }
#pragma unroll
      for (int kk = 0; kk < 4; ++kk) {
        half8 ah = *(const half8*)&h1b[rb][c][kk * 32 + q * 8];
        ar  = mfma16(ah, wh1r[kk], ar);
        az  = mfma16(ah, wh1z[kk], az);
        ahn = mfma16(ah, wh1n[kk], ahn);
      }
#pragma unroll
      for (int r = 0; r < 4; ++r) {
        float rg = sigm(ar[r]);
        float zg = sigm(az[r]);
        float ng = tanh_fast(fmaf(rg, ahn[r], ain[r]));
        float hn = fmaf(zg, h1p[r] - ng, ng);   // (1-z)*n + z*h
        h1p[r] = hn;
        h1b[wb][q * 4 + r][jc] = (half_t)hn;
      }
      __syncthreads();  // h1_new visible

      // ---------------- layer 2 ----------------
      f32x4 cr  = {b2r, b2r, b2r, b2r};
      f32x4 cz  = {b2z, b2z, b2z, b2z};
      f32x4 cin = {b2in, b2in, b2in, b2in};
      f32x4 chn = {b2hn, b2hn, b2hn, b2hn};
#pragma unroll
      for (int kk = 0; kk < 4; ++kk) {
        half8 a1 = *(const half8*)&h1b[wb][c][kk * 32 + q * 8];  // h1_new
        half8 a2 = *(const half8*)&h2b[rb][c][kk * 32 + q * 8];  // h2_prev
        cr  = mfma16(a1, wi2r[kk], cr);
        cz  = mfma16(a1, wi2z[kk], cz);
        cin = mfma16(a1, wi2n[kk], cin);
        cr  = mfma16(a2, wh2r[kk], cr);
        cz  = mfma16(a2, wh2z[kk], cz);
        chn = mfma16(a2, wh2n[kk], chn);
      }
#pragma unroll
      for (int r = 0; r < 4; ++r) {
        float rg = sigm(cr[r]);
        float zg = sigm(cz[r]);
        float ng = tanh_fast(fmaf(rg, chn[r], cin[r]));
        float hn = fmaf(zg, h2p[r] - ng, ng);
        h2p[r] = hn;
        h2b[wb][q * 4 + r][jc] = (half_t)hn;
      }
      __syncthreads();  // h2_new visible for next step
    }
  }

  // ---------------- FC epilogue (pure fp32) ----------------
#pragma unroll
  for (int r = 0; r < 4; ++r) h2f[q * 4 + r][jc] = h2p[r];
  __syncthreads();
  if (tid < 384) {
    const int m = tid & 15;
    const int cls = tid >> 4;  // 0..23
    const float* w = fcw + cls * 128;
    float acc = fcb[cls];
#pragma unroll 8
    for (int j = 0; j < 128; ++j) acc = fmaf(h2f[m][j], w[j], acc);
    out[(size_t)(s0 + m) * 24 + cls] = acc;
  }
}

extern "C" void kernel_launch(void* const* d_in, const int* in_sizes, int n_in,
                              void* d_out, int out_size, void* d_ws, size_t ws_size,
                              hipStream_t stream) {
  (void)in_sizes; (void)n_in; (void)d_ws; (void)ws_size; (void)out_size;
  const float* x    = (const float*)d_in[0];
  const float* wih1 = (const float*)d_in[1];
  const float* whh1 = (const float*)d_in[2];
  const float* bih1 = (const float*)d_in[3];
  const float* bhh1 = (const float*)d_in[4];
  const float* wih2 = (const float*)d_in[5];
  const float* whh2 = (const float*)d_in[6];
  const float* bih2 = (const float*)d_in[7];
  const float* bhh2 = (const float*)d_in[8];
  const float* fcw  = (const float*)d_in[9];
  const float* fcb  = (const float*)d_in[10];
  float* outp = (float*)d_out;
  gru_fused<<<dim3(256), dim3(512), 0, stream>>>(
      x, wih1, whh1, bih1, bhh1, wih2, whh2, bih2, bhh2, fcw, fcb, outp);
}

// Round 3
// 277.327 us; speedup vs baseline: 1.4147x; 1.4087x over previous
//
#include <hip/hip_runtime.h>

// Fused 2-layer GRU + FC for (B=4096, L=128, IN=16, H=128, NC=24).
// 256 blocks x 512 threads (1 block/CU); block = 16 batch rows, wave w owns
// h-cols [16w,16w+16). Weights pinned in VGPRs via empty inline asm (round 2
// showed the compiler rematerializes ~290KB/block/step of weight loads from
// L1/L2 otherwise). Layer2 runs one step behind layer1 => single barrier per
// step and 39 independent MFMAs of ILP per barrier interval.

typedef _Float16 half_t;
typedef _Float16 half8 __attribute__((ext_vector_type(8)));
typedef _Float16 half4v __attribute__((ext_vector_type(4)));
typedef float f32x4 __attribute__((ext_vector_type(4)));

#define BB 16      // batch rows per block
#define HS 136     // h row stride (halves), 16B-aligned rows
#define XS 520     // x chunk row stride (halves): 32*16 + 8 pad

static __device__ __forceinline__ f32x4 mfma16(half8 a, half8 b, f32x4 c) {
  return __builtin_amdgcn_mfma_f32_16x16x32_f16(a, b, c, 0, 0, 0);
}

// Pin a fragment into registers: value becomes asm-defined => cannot be
// rematerialized from global memory inside the recurrence loop.
static __device__ __forceinline__ void pin(half8& v) {
  f32x4 t = __builtin_bit_cast(f32x4, v);
  asm volatile("" : "+v"(t));
  v = __builtin_bit_cast(half8, t);
}

static __device__ __forceinline__ half8 zero8() {
  half8 v;
#pragma unroll
  for (int i = 0; i < 8; ++i) v[i] = (half_t)0.f;
  return v;
}

static __device__ __forceinline__ half8 ldw8(const float* __restrict__ p) {
  float4 a = *(const float4*)p;
  float4 b = *(const float4*)(p + 4);
  half8 r;
  r[0] = (half_t)a.x; r[1] = (half_t)a.y; r[2] = (half_t)a.z; r[3] = (half_t)a.w;
  r[4] = (half_t)b.x; r[5] = (half_t)b.y; r[6] = (half_t)b.z; r[7] = (half_t)b.w;
  return r;
}

static __device__ __forceinline__ float sigm(float v) {
  return __builtin_amdgcn_rcpf(1.f + __expf(-v));
}
static __device__ __forceinline__ float tanh_fast(float v) {
  float e = __expf(2.f * v);
  return 1.f - 2.f * __builtin_amdgcn_rcpf(1.f + e);
}

__global__ __launch_bounds__(512, 2) void gru_fused(
    const float* __restrict__ x,                                    // (4096,2,1024)
    const float* __restrict__ wih1, const float* __restrict__ whh1, // (384,16),(384,128)
    const float* __restrict__ bih1, const float* __restrict__ bhh1,
    const float* __restrict__ wih2, const float* __restrict__ whh2, // (384,128)x2
    const float* __restrict__ bih2, const float* __restrict__ bhh2,
    const float* __restrict__ fcw, const float* __restrict__ fcb,   // (24,128),(24,)
    float* __restrict__ out)                                        // (4096,24)
{
  __shared__ __align__(16) half_t xl[BB][XS];        // 16640 B
  __shared__ __align__(16) half_t h1b[2][BB][HS];    //  8704 B
  __shared__ __align__(16) half_t h2b[2][BB][HS];    //  8704 B
  __shared__ float h2f[BB][129];                     //  8256 B

  const int tid = threadIdx.x;
  const int lane = tid & 63;
  const int wv = tid >> 6;      // wave 0..7
  const int q = lane >> 4;      // quad 0..3
  const int c = lane & 15;
  const int jc = wv * 16 + c;   // this lane's h-column (0..127)
  const int s0 = blockIdx.x * BB;

  // zero both parity buffers of both states (layer2 MFMAs run unguarded at i=0)
  for (int i = tid; i < 2 * BB * HS; i += 512) {
    ((half_t*)h1b)[i] = (half_t)0.f;
    ((half_t*)h2b)[i] = (half_t)0.f;
  }

  // biases (r/z fold b_ih+b_hh; n keeps them split for r*(Wh+b_hh) semantics)
  const float b1r  = bih1[jc]       + bhh1[jc];
  const float b1z  = bih1[128 + jc] + bhh1[128 + jc];
  const float b1in = bih1[256 + jc];
  const float b1hn = bhh1[256 + jc];
  const float b2r  = bih2[jc]       + bhh2[jc];
  const float b2z  = bih2[128 + jc] + bhh2[128 + jc];
  const float b2in = bih2[256 + jc];
  const float b2hn = bhh2[256 + jc];

  // weight B-fragments: lane holds W[n=jc(+g*128)][k = kk*32 + q*8 + j]
  half8 wi1r, wi1z, wi1n;
  if (q < 2) {  // real K=16, quads 2..3 are zero-pad
    wi1r = ldw8(wih1 + (0 * 128 + jc) * 16 + q * 8);
    wi1z = ldw8(wih1 + (1 * 128 + jc) * 16 + q * 8);
    wi1n = ldw8(wih1 + (2 * 128 + jc) * 16 + q * 8);
  } else {
    wi1r = zero8(); wi1z = zero8(); wi1n = zero8();
  }
  pin(wi1r); pin(wi1z); pin(wi1n);

  half8 wh1r[4], wh1z[4], wh1n[4], wi2r[4], wi2z[4], wi2n[4], wh2r[4], wh2z[4], wh2n[4];
#pragma unroll
  for (int kk = 0; kk < 4; ++kk) {
    const int ko = kk * 32 + q * 8;
    wh1r[kk] = ldw8(whh1 + (0 * 128 + jc) * 128 + ko);
    wh1z[kk] = ldw8(whh1 + (1 * 128 + jc) * 128 + ko);
    wh1n[kk] = ldw8(whh1 + (2 * 128 + jc) * 128 + ko);
    wi2r[kk] = ldw8(wih2 + (0 * 128 + jc) * 128 + ko);
    wi2z[kk] = ldw8(wih2 + (1 * 128 + jc) * 128 + ko);
    wi2n[kk] = ldw8(wih2 + (2 * 128 + jc) * 128 + ko);
    wh2r[kk] = ldw8(whh2 + (0 * 128 + jc) * 128 + ko);
    wh2z[kk] = ldw8(whh2 + (1 * 128 + jc) * 128 + ko);
    wh2n[kk] = ldw8(whh2 + (2 * 128 + jc) * 128 + ko);
    pin(wh1r[kk]); pin(wh1z[kk]); pin(wh1n[kk]);
    pin(wi2r[kk]); pin(wi2z[kk]); pin(wi2n[kk]);
    pin(wh2r[kk]); pin(wh2z[kk]); pin(wh2n[kk]);
  }

  // fp32 hidden state, lane-resident: rows m = 4q+r, col jc
  float h1p[4] = {0.f, 0.f, 0.f, 0.f};
  float h2p[4] = {0.f, 0.f, 0.f, 0.f};

  for (int tc = 0; tc < 4; ++tc) {
    // stage x[s][ch][tc*256 .. +255] -> xl[s][tl*16 + ch*8 + k], fp16
#pragma unroll
    for (int it = 0; it < 4; ++it) {
      int idx = tid + it * 512;         // 0..2047 float4s
      int s = idx >> 7;
      int rem = idx & 127;
      int ch = rem >> 6;
      int i4 = rem & 63;
      const float4 v = *(const float4*)(x + (size_t)(s0 + s) * 2048 + ch * 1024 + tc * 256 + i4 * 4);
      half4v hv;
      hv[0] = (half_t)v.x; hv[1] = (half_t)v.y; hv[2] = (half_t)v.z; hv[3] = (half_t)v.w;
      *(half4v*)&xl[s][(i4 >> 1) * 16 + ch * 8 + (i4 & 1) * 4] = hv;
    }
    __syncthreads();

    for (int tt = 0; tt < 32; ++tt) {
      const int i = tc * 32 + tt;      // layer1 step index; layer2 does step i-1
      const int rb = i & 1;
      const int wb = rb ^ 1;

      f32x4 ar  = {b1r, b1r, b1r, b1r};
      f32x4 az  = {b1z, b1z, b1z, b1z};
      f32x4 ain = {b1in, b1in, b1in, b1in};
      f32x4 ahn = {b1hn, b1hn, b1hn, b1hn};
      f32x4 cr  = {b2r, b2r, b2r, b2r};
      f32x4 cz  = {b2z, b2z, b2z, b2z};
      f32x4 cin = {b2in, b2in, b2in, b2in};
      f32x4 chn = {b2hn, b2hn, b2hn, b2hn};

      {
        half8 ax = zero8();
        if (q < 2) ax = *(const half8*)&xl[c][tt * 16 + q * 8];
        ar  = mfma16(ax, wi1r, ar);
        az  = mfma16(ax, wi1z, az);
        ain = mfma16(ax, wi1n, ain);
      }
#pragma unroll
      for (int kk = 0; kk < 4; ++kk) {
        half8 ah = *(const half8*)&h1b[rb][c][kk * 32 + q * 8];  // h1[i-1]
        half8 a2 = *(const half8*)&h2b[rb][c][kk * 32 + q * 8];  // h2[i-2]
        ar  = mfma16(ah, wh1r[kk], ar);
        az  = mfma16(ah, wh1z[kk], az);
        ahn = mfma16(ah, wh1n[kk], ahn);
        cr  = mfma16(ah, wi2r[kk], cr);   // layer2 input = h1[i-1]
        cz  = mfma16(ah, wi2z[kk], cz);
        cin = mfma16(ah, wi2n[kk], cin);
        cr  = mfma16(a2, wh2r[kk], cr);
        cz  = mfma16(a2, wh2z[kk], cz);
        chn = mfma16(a2, wh2n[kk], chn);
      }

      // layer1 epilogue: h1[i]
#pragma unroll
      for (int r = 0; r < 4; ++r) {
        float rg = sigm(ar[r]);
        float zg = sigm(az[r]);
        float ng = tanh_fast(fmaf(rg, ahn[r], ain[r]));
        float hn = fmaf(zg, h1p[r] - ng, ng);   // (1-z)*n + z*h
        h1p[r] = hn;
        h1b[wb][q * 4 + r][jc] = (half_t)hn;
      }
      // layer2 epilogue: h2[i-1] (skip at i==0; its MFMA inputs were zeros)
      if (i > 0) {
#pragma unroll
        for (int r = 0; r < 4; ++r) {
          float rg = sigm(cr[r]);
          float zg = sigm(cz[r]);
          float ng = tanh_fast(fmaf(rg, chn[r], cin[r]));
          float hn = fmaf(zg, h2p[r] - ng, ng);
          h2p[r] = hn;
          h2b[wb][q * 4 + r][jc] = (half_t)hn;
        }
      }
      __syncthreads();
    }
  }

  // final layer2 step 127: h1[127] & h2[126] live in parity-0 buffers (i=128)
  {
    f32x4 cr  = {b2r, b2r, b2r, b2r};
    f32x4 cz  = {b2z, b2z, b2z, b2z};
    f32x4 cin = {b2in, b2in, b2in, b2in};
    f32x4 chn = {b2hn, b2hn, b2hn, b2hn};
#pragma unroll
    for (int kk = 0; kk < 4; ++kk) {
      half8 a1 = *(const half8*)&h1b[0][c][kk * 32 + q * 8];
      half8 a2 = *(const half8*)&h2b[0][c][kk * 32 + q * 8];
      cr  = mfma16(a1, wi2r[kk], cr);
      cz  = mfma16(a1, wi2z[kk], cz);
      cin = mfma16(a1, wi2n[kk], cin);
      cr  = mfma16(a2, wh2r[kk], cr);
      cz  = mfma16(a2, wh2z[kk], cz);
      chn = mfma16(a2, wh2n[kk], chn);
    }
#pragma unroll
    for (int r = 0; r < 4; ++r) {
      float rg = sigm(cr[r]);
      float zg = sigm(cz[r]);
      float ng = tanh_fast(fmaf(rg, chn[r], cin[r]));
      h2p[r] = fmaf(zg, h2p[r] - ng, ng);
    }
  }

  // ---------------- FC epilogue (pure fp32) ----------------
#pragma unroll
  for (int r = 0; r < 4; ++r) h2f[q * 4 + r][jc] = h2p[r];
  __syncthreads();
  if (tid < 384) {
    const int m = tid & 15;
    const int cls = tid >> 4;  // 0..23
    const float* w = fcw + cls * 128;
    float acc = fcb[cls];
#pragma unroll 8
    for (int j = 0; j < 128; ++j) acc = fmaf(h2f[m][j], w[j], acc);
    out[(size_t)(s0 + m) * 24 + cls] = acc;
  }
}

extern "C" void kernel_launch(void* const* d_in, const int* in_sizes, int n_in,
                              void* d_out, int out_size, void* d_ws, size_t ws_size,
                              hipStream_t stream) {
  (void)in_sizes; (void)n_in; (void)d_ws; (void)ws_size; (void)out_size;
  const float* x    = (const float*)d_in[0];
  const float* wih1 = (const float*)d_in[1];
  const float* whh1 = (const float*)d_in[2];
  const float* bih1 = (const float*)d_in[3];
  const float* bhh1 = (const float*)d_in[4];
  const float* wih2 = (const float*)d_in[5];
  const float* whh2 = (const float*)d_in[6];
  const float* bih2 = (const float*)d_in[7];
  const float* bhh2 = (const float*)d_in[8];
  const float* fcw  = (const float*)d_in[9];
  const float* fcb  = (const float*)d_in[10];
  float* outp = (float*)d_out;
  gru_fused<<<dim3(256), dim3(512), 0, stream>>>(
      x, wih1, whh1, bih1, bhh1, wih2, whh2, bih2, bhh2, fcw, fcb, outp);
}